// Round 16
// baseline (271.293 us; speedup 1.0000x reference)
//
#include <hip/hip_runtime.h>

#define F_IN 128
#define EPS_BN 1e-5f
#define NCOPY 8
#define NBLK 256          // sort blocks (64B runs per (bin,blk): full cache line)

typedef __attribute__((ext_vector_type(8))) short short8v;
typedef __attribute__((ext_vector_type(4))) float f32x4;
typedef __attribute__((ext_vector_type(2))) float f32x2;

__device__ __forceinline__ float lrelu(float x) { return x >= 0.f ? x : 0.2f * x; }
__device__ __forceinline__ unsigned short f2bf(float f) {
    unsigned int u = __float_as_uint(f);
    u += 0x7FFFu + ((u >> 16) & 1u);
    return (unsigned short)(u >> 16);
}
__device__ __forceinline__ float bf2f(unsigned short s) {
    return __uint_as_float(((unsigned int)s) << 16);
}
// unpack a uint holding 2 bf16 (lo=ch0, hi=ch1) into float2 — 2 VALU ops
__device__ __forceinline__ f32x2 bfpair(unsigned int u) {
    f32x2 r;
    r.x = __uint_as_float(u << 16);
    r.y = __uint_as_float(u & 0xFFFF0000u);
    return r;
}

// ================= CSR build via two-level counting sort (no device atomics) =================

// fused: per-block histogram (blocks < NBLK) + layer-0 prep (wave per node, all blocks)
__global__ void k_front(const int* __restrict__ ei, int e, int nbin, int* __restrict__ H,
                        const float* __restrict__ x, const float* __restrict__ vsd,
                        unsigned short* __restrict__ xb,
                        float* __restrict__ a_src, float* __restrict__ a_dst, int n)
{
    __shared__ int hist[256];
    int blk = blockIdx.x, tid = threadIdx.x;
    if (blk < NBLK) {
        if (tid < nbin) hist[tid] = 0;
        __syncthreads();
        int per = (e + NBLK - 1) / NBLK;
        int t0 = blk * per, t1 = min(t0 + per, e);
        for (int t = t0 + tid; t < t1; t += 256)
            atomicAdd(&hist[ei[e + t] >> 8], 1);
        __syncthreads();
        if (tid < nbin) H[tid * NBLK + blk] = hist[tid];
    }
    // prep0: wave per node
    int wv = (blk * blockDim.x + tid) >> 6;
    int lane = tid & 63;
    if (wv >= n) return;
    const int xo = lane << 1;
    float2 xv = *reinterpret_cast<const float2*>(&x[(size_t)wv * 128 + xo]);
    ushort2 o;
    o.x = f2bf(xv.x); o.y = f2bf(xv.y);
    *reinterpret_cast<ushort2*>(&xb[(size_t)wv * 128 + xo]) = o;
    float ps[4], pd[4];
    #pragma unroll
    for (int h = 0; h < 4; h++) {
        float2 v2 = *reinterpret_cast<const float2*>(&vsd[h * 128 + xo]);
        float2 w2 = *reinterpret_cast<const float2*>(&vsd[512 + h * 128 + xo]);
        ps[h] = xv.x * v2.x + xv.y * v2.y;
        pd[h] = xv.x * w2.x + xv.y * w2.y;
    }
    #pragma unroll
    for (int off = 32; off; off >>= 1) {
        #pragma unroll
        for (int h = 0; h < 4; h++) {
            ps[h] += __shfl_xor(ps[h], off);
            pd[h] += __shfl_xor(pd[h], off);
        }
    }
    if (lane == 0) {
        *reinterpret_cast<float4*>(&a_src[wv * 4]) = make_float4(ps[0], ps[1], ps[2], ps[3]);
        *reinterpret_cast<float4*>(&a_dst[wv * 4]) = make_float4(pd[0], pd[1], pd[2], pd[3]);
    }
}

__global__ void k_scanbins(const int* __restrict__ H, int* __restrict__ Hc,
                           int* __restrict__ bintot, int nbin) {
    int wv = (blockIdx.x * blockDim.x + threadIdx.x) >> 6;
    int lane = threadIdx.x & 63;
    if (wv >= nbin) return;
    int carry = 0;
    for (int c = 0; c < NBLK; c += 64) {
        int v = H[wv * NBLK + c + lane];
        int s = v;
        #pragma unroll
        for (int off = 1; off < 64; off <<= 1) {
            int u = __shfl_up(s, off);
            if (lane >= off) s += u;
        }
        Hc[wv * NBLK + c + lane] = carry + s - v;   // exclusive
        carry += __shfl(s, 63);
    }
    if (lane == 0) bintot[wv] = carry;
}

__global__ void k_scanbase(const int* __restrict__ bintot, int* __restrict__ SEbase, int nbin) {
    __shared__ int buf[256];
    int tid = threadIdx.x;
    if (tid < nbin) buf[tid] = bintot[tid];
    __syncthreads();
    if (tid == 0) {
        int run = 0;
        for (int b = 0; b < nbin; b++) { SEbase[b] = run; run += buf[b]; }
        SEbase[nbin] = run;
    }
}

__global__ void k_scatter(const int* __restrict__ ei, int e, const int* __restrict__ Hc,
                          const int* __restrict__ SEbase, unsigned int* __restrict__ SE, int nbin) {
    __shared__ int cur[256];
    int blk = blockIdx.x, tid = threadIdx.x;
    if (tid < nbin) cur[tid] = SEbase[tid] + Hc[tid * NBLK + blk];
    __syncthreads();
    int per = (e + NBLK - 1) / NBLK;
    int t0 = blk * per, t1 = min(t0 + per, e);
    for (int t = t0 + tid; t < t1; t += 256) {
        int s = ei[t], d = ei[e + t];
        int pos = atomicAdd(&cur[d >> 8], 1);     // LDS atomic (block-local)
        SE[pos] = ((unsigned int)d << 16) | (unsigned int)s;
    }
}

__global__ void k_degb(const unsigned int* __restrict__ SE, const int* __restrict__ SEbase,
                       int* __restrict__ deg, int* __restrict__ binpad, int n) {
    __shared__ int hist[256];
    __shared__ int red[256];
    int b = blockIdx.x, tid = threadIdx.x;
    hist[tid] = 0;
    __syncthreads();
    int t0 = SEbase[b], t1 = SEbase[b + 1];
    for (int t = t0 + tid; t < t1; t += 256)
        atomicAdd(&hist[(int)(SE[t] >> 16) - (b << 8)], 1);
    __syncthreads();
    int dst = (b << 8) + tid;
    int dv = hist[tid];
    if (dst < n) deg[dst] = dv;
    red[tid] = (dst < n) ? ((dv + 7) & ~7) : 0;
    __syncthreads();
    #pragma unroll
    for (int s = 128; s; s >>= 1) {
        if (tid < s) red[tid] += red[tid + s];
        __syncthreads();
    }
    if (tid == 0) binpad[b] = red[0];
}

__global__ void k_binscan(const int* __restrict__ binpad, int* __restrict__ binbase, int nbin) {
    __shared__ int buf[256];
    int tid = threadIdx.x;
    int pv = (tid < nbin) ? binpad[tid] : 0;
    buf[tid] = pv;
    __syncthreads();
    for (int off = 1; off < 256; off <<= 1) {
        int v = (tid >= off) ? buf[tid - off] : 0;
        __syncthreads();
        buf[tid] += v;
        __syncthreads();
    }
    if (tid < nbin) binbase[tid] = buf[tid] - pv;   // exclusive
}

__global__ void k_fillb(const unsigned int* __restrict__ SE, const int* __restrict__ SEbase,
                        const int* __restrict__ binbase, const int* __restrict__ deg,
                        int* __restrict__ col, int* __restrict__ startp, int n) {
    __shared__ int sps[256];
    __shared__ int cur[256];
    int b = blockIdx.x, tid = threadIdx.x;
    int dst = (b << 8) + tid;
    int pv = (dst < n) ? ((deg[dst] + 7) & ~7) : 0;
    sps[tid] = pv;
    __syncthreads();
    for (int off = 1; off < 256; off <<= 1) {
        int v = (tid >= off) ? sps[tid - off] : 0;
        __syncthreads();
        sps[tid] += v;
        __syncthreads();
    }
    int sp = binbase[b] + sps[tid] - pv;   // exclusive
    if (dst < n) startp[dst] = sp;
    cur[tid] = sp;
    __syncthreads();
    int t0 = SEbase[b], t1 = SEbase[b + 1];
    for (int t = t0 + tid; t < t1; t += 256) {
        unsigned int se = SE[t];
        int pos = atomicAdd(&cur[(int)(se >> 16) - (b << 8)], 1);   // LDS atomic
        col[pos] = (int)(se & 0xFFFFu);
    }
    __syncthreads();
    if (dst < n) {
        int p = cur[tid];                                   // = sp + deg
        int pe = sp + pv;
        for (; p < pe; p++) col[p] = n;
    }
}

// ---------------- weight prep + layer-0 score vectors + dummy score slot ----------------
__global__ void k_wprep_all(const float* __restrict__ W0, const float* __restrict__ W1,
                            const float* __restrict__ W2, const float* __restrict__ lw1,
                            const float* __restrict__ as0, const float* __restrict__ ad0,
                            unsigned short* __restrict__ Wt0, unsigned short* __restrict__ Wt1,
                            unsigned short* __restrict__ Wt2, unsigned short* __restrict__ Wtm,
                            float* __restrict__ vsd, float* __restrict__ a_src, int n)
{
    int t = blockIdx.x * blockDim.x + threadIdx.x;
    if (t < 32768) {               // W0: K=128, Nc=256
        int nn = t / 128, kk = t - nn * 128;
        Wt0[t] = f2bf(W0[(size_t)kk * 256 + nn]);
    } else if (t < 49152) {        // W1: K=256, Nc=64
        int u = t - 32768;
        int nn = u / 256, kk = u - nn * 256;
        Wt1[u] = f2bf(W1[(size_t)kk * 64 + nn]);
    } else if (t < 53248) {        // W2: K=64, Nc=64
        int u = t - 49152;
        int nn = u / 64, kk = u - nn * 64;
        Wt2[u] = f2bf(W2[(size_t)kk * 64 + nn]);
    } else if (t < 57344) {        // lw1: K=64, Nc=64
        int u = t - 53248;
        int nn = u / 64, kk = u - nn * 64;
        Wtm[u] = f2bf(lw1[(size_t)kk * 64 + nn]);
    } else if (t < 57856) {        // vs[h][k]
        int u = t - 57344;
        int h = u >> 7, k = u & 127;
        float s = 0.f;
        for (int d2 = 0; d2 < 64; d2++) s += W0[(size_t)k * 256 + h * 64 + d2] * as0[h * 64 + d2];
        vsd[u] = s;
    } else if (t < 58368) {        // vd[h][k]
        int u = t - 57856;
        int h = u >> 7, k = u & 127;
        float s = 0.f;
        for (int d2 = 0; d2 < 64; d2++) s += W0[(size_t)k * 256 + h * 64 + d2] * ad0[h * 64 + d2];
        vsd[512 + u] = s;
    } else if (t < 58372) {        // dummy-node H=4 score slot: exp(-inf)=0
        a_src[4 * n + (t - 58368)] = -1e30f;
    }
}

// ---------------- layer-0 aggregation over x: 8 edges/iter, packed-fp32 accumulate ----------------
__global__ void k_aggx4(const unsigned short* __restrict__ xb,
                        const float* __restrict__ asrc, const float* __restrict__ adst,
                        const int* __restrict__ startp, const int* __restrict__ deg,
                        const int* __restrict__ col,
                        unsigned short* __restrict__ aggx, int n)
{
    __shared__ float lds_w[4][64];
    int wv = (blockIdx.x * blockDim.x + threadIdx.x) >> 6;
    int lane = threadIdx.x & 63;
    int wid = threadIdx.x >> 6;
    if (wv >= n) return;
    const int s0 = startp[wv], d = deg[wv];
    const int dpad = (d + 7) & ~7;
    const int eslot = (lane & 31) >> 2;
    const int hslot = lane & 3;
    const float4 adh4 = *reinterpret_cast<const float4*>(&adst[wv * 4]);
    const float4 asf4 = *reinterpret_cast<const float4*>(&asrc[wv * 4]);
    const float adh_h = hslot == 0 ? adh4.x : hslot == 1 ? adh4.y :
                        hslot == 2 ? adh4.z : adh4.w;
    const float w0 = __expf(lrelu(asf4.x + adh4.x));
    const float w1 = __expf(lrelu(asf4.y + adh4.y));
    const float w2 = __expf(lrelu(asf4.z + adh4.z));
    const float w3 = __expf(lrelu(asf4.w + adh4.w));
    const unsigned int* xbu = reinterpret_cast<const unsigned int*>(xb);  // 64 uints/row
    f32x2 xv = bfpair(xbu[(size_t)wv * 64 + lane]);
    f32x2 A0 = w0 * xv, A1 = w1 * xv, A2 = w2 * xv, A3 = w3 * xv;
    float wsum = 0.f;
    const int* crow = col + s0;
    const float* asrcp = asrc + hslot;
    for (int t = 0; t < dpad; t += 8) {
        int se = crow[t + eslot];
        float wme = __expf(lrelu(asrcp[se * 4] + adh_h));
        wsum += wme;
        lds_w[wid][lane] = wme;
        int4 c0 = *reinterpret_cast<const int4*>(&crow[t]);
        int4 c1 = *reinterpret_cast<const int4*>(&crow[t + 4]);
        f32x2 xA = bfpair(xbu[(size_t)c0.x * 64 + lane]);
        f32x2 xB = bfpair(xbu[(size_t)c0.y * 64 + lane]);
        f32x2 xC = bfpair(xbu[(size_t)c0.z * 64 + lane]);
        f32x2 xD = bfpair(xbu[(size_t)c0.w * 64 + lane]);
        f32x2 xE = bfpair(xbu[(size_t)c1.x * 64 + lane]);
        f32x2 xF = bfpair(xbu[(size_t)c1.y * 64 + lane]);
        f32x2 xG = bfpair(xbu[(size_t)c1.z * 64 + lane]);
        f32x2 xH = bfpair(xbu[(size_t)c1.w * 64 + lane]);
        float4 wA = *reinterpret_cast<const float4*>(&lds_w[wid][0]);
        float4 wB = *reinterpret_cast<const float4*>(&lds_w[wid][4]);
        float4 wC = *reinterpret_cast<const float4*>(&lds_w[wid][8]);
        float4 wD = *reinterpret_cast<const float4*>(&lds_w[wid][12]);
        float4 wE = *reinterpret_cast<const float4*>(&lds_w[wid][16]);
        float4 wF = *reinterpret_cast<const float4*>(&lds_w[wid][20]);
        float4 wG = *reinterpret_cast<const float4*>(&lds_w[wid][24]);
        float4 wH = *reinterpret_cast<const float4*>(&lds_w[wid][28]);
        A0 += wA.x * xA; A0 += wB.x * xB; A0 += wC.x * xC; A0 += wD.x * xD;
        A0 += wE.x * xE; A0 += wF.x * xF; A0 += wG.x * xG; A0 += wH.x * xH;
        A1 += wA.y * xA; A1 += wB.y * xB; A1 += wC.y * xC; A1 += wD.y * xD;
        A1 += wE.y * xE; A1 += wF.y * xF; A1 += wG.y * xG; A1 += wH.y * xH;
        A2 += wA.z * xA; A2 += wB.z * xB; A2 += wC.z * xC; A2 += wD.z * xD;
        A2 += wE.z * xE; A2 += wF.z * xF; A2 += wG.z * xG; A2 += wH.z * xH;
        A3 += wA.w * xA; A3 += wB.w * xB; A3 += wC.w * xC; A3 += wD.w * xD;
        A3 += wE.w * xE; A3 += wF.w * xF; A3 += wG.w * xG; A3 += wH.w * xH;
    }
    wsum += __shfl_xor(wsum, 4);
    wsum += __shfl_xor(wsum, 8);
    wsum += __shfl_xor(wsum, 16);
    float r0 = 1.f / (w0 + __shfl(wsum, 0) + 1e-16f);
    float r1 = 1.f / (w1 + __shfl(wsum, 1) + 1e-16f);
    float r2 = 1.f / (w2 + __shfl(wsum, 2) + 1e-16f);
    float r3 = 1.f / (w3 + __shfl(wsum, 3) + 1e-16f);
    const int xo = lane << 1;
    size_t base = (size_t)wv * 512 + xo;
    ushort2 o;
    o.x = f2bf(A0.x * r0); o.y = f2bf(A0.y * r0);
    *reinterpret_cast<ushort2*>(&aggx[base]) = o;
    o.x = f2bf(A1.x * r1); o.y = f2bf(A1.y * r1);
    *reinterpret_cast<ushort2*>(&aggx[base + 128]) = o;
    o.x = f2bf(A2.x * r2); o.y = f2bf(A2.y * r2);
    *reinterpret_cast<ushort2*>(&aggx[base + 256]) = o;
    o.x = f2bf(A3.x * r3); o.y = f2bf(A3.y * r3);
    *reinterpret_cast<ushort2*>(&aggx[base + 384]) = o;
}

// ---------------- layer-0 block-diagonal GEMM: out0b = bf16(aggx_bd @ W0 + b0) ----------------
__global__ __launch_bounds__(256) void k_gemm_bd(
    const unsigned short* __restrict__ Ab, const unsigned short* __restrict__ Wt,
    const float* __restrict__ bias, unsigned short* __restrict__ Cb0,
    float* __restrict__ ostats, int M)
{
    __shared__ unsigned short As[64 * 136];
    __shared__ unsigned short Bs[64 * 136];
    __shared__ float sred[4][4][16], sred2[4][4][16];
    const int tid = threadIdx.x;
    const int w = tid >> 6, lane = tid & 63;
    const int l15 = lane & 15, g = lane >> 4;
    const int bm = blockIdx.x * 64, bn = blockIdx.y * 64;
    const int hh = blockIdx.y;
    const int srow = tid >> 2;
    const int sk = (tid & 3) << 5;

    {
        short8v a0, a1, a2, a3;
        if (bm + srow < M) {
            const unsigned short* ap = &Ab[(size_t)(bm + srow) * 512 + hh * 128 + sk];
            a0 = *reinterpret_cast<const short8v*>(ap);
            a1 = *reinterpret_cast<const short8v*>(ap + 8);
            a2 = *reinterpret_cast<const short8v*>(ap + 16);
            a3 = *reinterpret_cast<const short8v*>(ap + 24);
        } else {
            a0 = a1 = a2 = a3 = (short8v){0,0,0,0,0,0,0,0};
        }
        const unsigned short* bp = &Wt[(size_t)(bn + srow) * 128 + sk];
        short8v b0v = *reinterpret_cast<const short8v*>(bp);
        short8v b1v = *reinterpret_cast<const short8v*>(bp + 8);
        short8v b2v = *reinterpret_cast<const short8v*>(bp + 16);
        short8v b3v = *reinterpret_cast<const short8v*>(bp + 24);
        unsigned short* arow = &As[srow * 136 + sk];
        *reinterpret_cast<short8v*>(arow) = a0;
        *reinterpret_cast<short8v*>(arow + 8) = a1;
        *reinterpret_cast<short8v*>(arow + 16) = a2;
        *reinterpret_cast<short8v*>(arow + 24) = a3;
        unsigned short* brow = &Bs[srow * 136 + sk];
        *reinterpret_cast<short8v*>(brow) = b0v;
        *reinterpret_cast<short8v*>(brow + 8) = b1v;
        *reinterpret_cast<short8v*>(brow + 16) = b2v;
        *reinterpret_cast<short8v*>(brow + 24) = b3v;
    }
    __syncthreads();

    f32x4 acc[4];
    #pragma unroll
    for (int nt = 0; nt < 4; nt++) acc[nt] = (f32x4){0.f, 0.f, 0.f, 0.f};
    #pragma unroll
    for (int kk = 0; kk < 4; kk++) {
        short8v af = *reinterpret_cast<const short8v*>(&As[(w * 16 + l15) * 136 + kk * 32 + g * 8]);
        #pragma unroll
        for (int nt = 0; nt < 4; nt++) {
            short8v bf = *reinterpret_cast<const short8v*>(&Bs[(nt * 16 + l15) * 136 + kk * 32 + g * 8]);
            acc[nt] = __builtin_amdgcn_mfma_f32_16x16x32_bf16(af, bf, acc[nt], 0, 0, 0);
        }
    }

    float s[4] = {0.f, 0.f, 0.f, 0.f}, s2[4] = {0.f, 0.f, 0.f, 0.f};
    #pragma unroll
    for (int reg = 0; reg < 4; reg++) {
        int row = bm + w * 16 + g * 4 + reg;
        if (row < M) {
            #pragma unroll
            for (int nt = 0; nt < 4; nt++) {
                float v = acc[nt][reg] + bias[bn + nt * 16 + l15];
                Cb0[(size_t)row * 256 + bn + nt * 16 + l15] = f2bf(v);
                s[nt] += v; s2[nt] += v * v;
            }
        }
    }
    #pragma unroll
    for (int off = 16; off <= 32; off <<= 1) {
        #pragma unroll
        for (int nt = 0; nt < 4; nt++) {
            s[nt]  += __shfl_xor(s[nt], off);
            s2[nt] += __shfl_xor(s2[nt], off);
        }
    }
    if (g == 0) {
        #pragma unroll
        for (int nt = 0; nt < 4; nt++) { sred[w][nt][l15] = s[nt]; sred2[w][nt][l15] = s2[nt]; }
    }
    __syncthreads();
    if (tid < 64) {
        int nt = tid >> 4, c = tid & 15;
        float S = 0.f, S2 = 0.f;
        #pragma unroll
        for (int w4 = 0; w4 < 4; w4++) { S += sred[w4][nt][c]; S2 += sred2[w4][nt][c]; }
        float* dst = ostats + (blockIdx.x & (NCOPY - 1)) * 512 + bn;
        atomicAdd(&dst[tid], S);
        atomicAdd(&dst[256 + tid], S2);
    }
}

// ---------------- bf16 MFMA GEMM (layers 1,2, MLP) ----------------
template<bool BN, bool ATT, bool AB16>
__global__ __launch_bounds__(256) void k_gemm(
    const float* __restrict__ Af, const unsigned short* __restrict__ Abf,
    const unsigned short* __restrict__ Wt,
    const float* __restrict__ bias,
    const float* __restrict__ bnst, float invN,
    const float* __restrict__ att_s, const float* __restrict__ att_d,
    float* __restrict__ a_src, float* __restrict__ a_dst, int H,
    float* __restrict__ Cf, unsigned short* __restrict__ Cb,
    float* __restrict__ ostats,
    int M, int K, int Nc)
{
    __shared__ unsigned short As[64 * 40];
    __shared__ unsigned short Bs[64 * 40];
    __shared__ float muS[256], rsS[256];
    const int tid = threadIdx.x;
    const int w = tid >> 6, lane = tid & 63;
    const int l15 = lane & 15, g = lane >> 4;
    const int bm = blockIdx.x * 64, bn = blockIdx.y * 64;
    const int srow = tid >> 2;
    const int skq  = (tid & 3) << 3;

    if constexpr (BN) {
        if (tid < K) {
            float s = 0.f, s2 = 0.f;
            #pragma unroll
            for (int c = 0; c < NCOPY; c++) {
                s  += bnst[c * 2 * K + tid];
                s2 += bnst[c * 2 * K + K + tid];
            }
            float m = s * invN;
            float var = s2 * invN - m * m;
            muS[tid] = m;
            rsS[tid] = rsqrtf(var + EPS_BN);
        }
        __syncthreads();
    }

    f32x4 acc[4];
    #pragma unroll
    for (int nt = 0; nt < 4; nt++) acc[nt] = (f32x4){0.f, 0.f, 0.f, 0.f};

    for (int k0 = 0; k0 < K; k0 += 32) {
        short8v a8;
        if (bm + srow < M) {
            if constexpr (AB16) {
                short8v u = *reinterpret_cast<const short8v*>(&Abf[(size_t)(bm + srow) * K + k0 + skq]);
                if constexpr (BN) {
                    #pragma unroll
                    for (int j = 0; j < 8; j++) {
                        int kb = k0 + skq + j;
                        float f = bf2f((unsigned short)u[j]);
                        f = fmaxf((f - muS[kb]) * rsS[kb], 0.f);
                        a8[j] = (short)f2bf(f);
                    }
                } else {
                    a8 = u;
                }
            } else {
                const float* ap = &Af[(size_t)(bm + srow) * K + k0 + skq];
                float4 v0 = *reinterpret_cast<const float4*>(ap);
                float4 v1 = *reinterpret_cast<const float4*>(ap + 4);
                if constexpr (BN) {
                    int kb = k0 + skq;
                    v0.x = fmaxf((v0.x - muS[kb + 0]) * rsS[kb + 0], 0.f);
                    v0.y = fmaxf((v0.y - muS[kb + 1]) * rsS[kb + 1], 0.f);
                    v0.z = fmaxf((v0.z - muS[kb + 2]) * rsS[kb + 2], 0.f);
                    v0.w = fmaxf((v0.w - muS[kb + 3]) * rsS[kb + 3], 0.f);
                    v1.x = fmaxf((v1.x - muS[kb + 4]) * rsS[kb + 4], 0.f);
                    v1.y = fmaxf((v1.y - muS[kb + 5]) * rsS[kb + 5], 0.f);
                    v1.z = fmaxf((v1.z - muS[kb + 6]) * rsS[kb + 6], 0.f);
                    v1.w = fmaxf((v1.w - muS[kb + 7]) * rsS[kb + 7], 0.f);
                }
                a8[0] = (short)f2bf(v0.x); a8[1] = (short)f2bf(v0.y);
                a8[2] = (short)f2bf(v0.z); a8[3] = (short)f2bf(v0.w);
                a8[4] = (short)f2bf(v1.x); a8[5] = (short)f2bf(v1.y);
                a8[6] = (short)f2bf(v1.z); a8[7] = (short)f2bf(v1.w);
            }
        } else {
            a8 = (short8v){0,0,0,0,0,0,0,0};
        }
        short8v b8 = *reinterpret_cast<const short8v*>(&Wt[(size_t)(bn + srow) * K + k0 + skq]);
        __syncthreads();
        *reinterpret_cast<short8v*>(&As[srow * 40 + skq]) = a8;
        *reinterpret_cast<short8v*>(&Bs[srow * 40 + skq]) = b8;
        __syncthreads();
        short8v af = *reinterpret_cast<const short8v*>(&As[(w * 16 + l15) * 40 + g * 8]);
        #pragma unroll
        for (int nt = 0; nt < 4; nt++) {
            short8v bf = *reinterpret_cast<const short8v*>(&Bs[(nt * 16 + l15) * 40 + g * 8]);
            acc[nt] = __builtin_amdgcn_mfma_f32_16x16x32_bf16(af, bf, acc[nt], 0, 0, 0);
        }
    }

    if constexpr (ATT) {
        float wsv[4], wdv[4];
        #pragma unroll
        for (int nt = 0; nt < 4; nt++) {
            wsv[nt] = att_s[bn + nt * 16 + l15];
            wdv[nt] = att_d[bn + nt * 16 + l15];
        }
        #pragma unroll
        for (int reg = 0; reg < 4; reg++) {
            int row = bm + w * 16 + g * 4 + reg;
            float ps = 0.f, pd = 0.f;
            #pragma unroll
            for (int nt = 0; nt < 4; nt++) {
                float c = acc[nt][reg];
                ps += c * wsv[nt];
                pd += c * wdv[nt];
                if (row < M)
                    Cb[(size_t)row * Nc + bn + nt * 16 + l15] = f2bf(c);
            }
            #pragma unroll
            for (int off = 1; off < 16; off <<= 1) {
                ps += __shfl_xor(ps, off);
                pd += __shfl_xor(pd, off);
            }
            if (l15 == 0 && row < M) {
                int hh = bn >> 6;
                a_src[(size_t)row * H + hh] = ps;
                a_dst[(size_t)row * H + hh] = pd;
            }
        }
        // dummy slot for padded-CSR aggregation (H=1 layers): weight -> 0
        if (H == 1 && blockIdx.x == 0 && blockIdx.y == 0 && tid == 0)
            a_src[M] = -1e30f;
    } else {
        __shared__ float sred[4][4][16], sred2[4][4][16];
        float s[4] = {0.f, 0.f, 0.f, 0.f}, s2[4] = {0.f, 0.f, 0.f, 0.f};
        #pragma unroll
        for (int reg = 0; reg < 4; reg++) {
            int row = bm + w * 16 + g * 4 + reg;
            if (row < M) {
                #pragma unroll
                for (int nt = 0; nt < 4; nt++) {
                    float v = acc[nt][reg] + bias[bn + nt * 16 + l15];
                    Cf[(size_t)row * Nc + bn + nt * 16 + l15] = v;
                    s[nt] += v; s2[nt] += v * v;
                }
            }
        }
        #pragma unroll
        for (int off = 16; off <= 32; off <<= 1) {
            #pragma unroll
            for (int nt = 0; nt < 4; nt++) {
                s[nt]  += __shfl_xor(s[nt], off);
                s2[nt] += __shfl_xor(s2[nt], off);
            }
        }
        if (g == 0) {
            #pragma unroll
            for (int nt = 0; nt < 4; nt++) { sred[w][nt][l15] = s[nt]; sred2[w][nt][l15] = s2[nt]; }
        }
        __syncthreads();
        if (tid < 64) {
            int nt = tid >> 4, c = tid & 15;
            float S = 0.f, S2 = 0.f;
            #pragma unroll
            for (int w4 = 0; w4 < 4; w4++) { S += sred[w4][nt][c]; S2 += sred2[w4][nt][c]; }
            float* dst = ostats + (blockIdx.x & (NCOPY - 1)) * 128;
            atomicAdd(&dst[tid], S);
            atomicAdd(&dst[64 + tid], S2);
        }
    }
}

// ---------------- fused softmax aggregation + BN stats, H=1 ----------------
// Phase-split (aggx4 pattern): lane-specialized weights -> LDS; gather loop reads LDS.
__global__ void k_agg1f(const unsigned short* __restrict__ hb,
                        const float* __restrict__ asrc, const float* __restrict__ adst,
                        const int* __restrict__ startp, const int* __restrict__ deg,
                        const int* __restrict__ col, const float* __restrict__ bias,
                        float* __restrict__ out, float* __restrict__ ostats, int n)
{
    __shared__ float stage[4][64];
    __shared__ float lds_w[4][64];
    __shared__ int   lds_c[4][64];
    int wv = (blockIdx.x * blockDim.x + threadIdx.x) >> 6;
    int lane = threadIdx.x & 63;
    int w = threadIdx.x >> 6;
    const int g = lane >> 4, l16 = lane & 15;
    float4 o = make_float4(0.f, 0.f, 0.f, 0.f);
    const unsigned int* hbu = reinterpret_cast<const unsigned int*>(hb);  // 32 uints/row
    if (wv < n) {
        const int s0 = startp[wv], d = deg[wv];
        const int dpad = (d + 7) & ~7;
        const float adv = adst[wv];
        const float wself = __expf(lrelu(asrc[wv] + adv));
        f32x2 A01 = {0.f, 0.f}, A23 = {0.f, 0.f};
        float wsum = 0.f;
        if (g == 0) {
            uint2 u = *reinterpret_cast<const uint2*>(&hbu[(size_t)wv * 32 + (l16 << 1)]);
            A01 = wself * bfpair(u.x);
            A23 = wself * bfpair(u.y);
        }
        for (int c0 = 0; c0 < dpad; c0 += 64) {
            int rem = dpad - c0;               // > 0, multiple of 8
            // Phase A: lane computes ONE weight (coalesced col, 64 asrc gathers in flight)
            int s = n;
            float ww = 0.f;
            if (lane < rem) {
                s = col[s0 + c0 + lane];
                ww = __expf(lrelu(asrc[s] + adv));
            }
            lds_w[w][lane] = ww;
            lds_c[w][lane] = s;                // same-wave LDS: ordered, no barrier
            wsum += ww;
            // Phase B: group g gathers edges g, g+4, ... (weights/indices from LDS)
            int m = rem < 64 ? rem : 64;
            #pragma unroll 4
            for (int j = g; j < m; j += 4) {
                float wj = lds_w[w][j];
                int sj = lds_c[w][j];
                uint2 u = *reinterpret_cast<const uint2*>(&hbu[(size_t)sj * 32 + (l16 << 1)]);
                A01 += wj * bfpair(u.x);
                A23 += wj * bfpair(u.y);
            }
        }
        // denominator: each lane owns distinct edges -> full 64-lane butterfly
        #pragma unroll
        for (int off = 1; off < 64; off <<= 1) wsum += __shfl_xor(wsum, off);
        // accumulators: sum across the 4 groups
        #pragma unroll
        for (int off = 16; off <= 32; off <<= 1) {
            A01.x += __shfl_xor(A01.x, off); A01.y += __shfl_xor(A01.y, off);
            A23.x += __shfl_xor(A23.x, off); A23.y += __shfl_xor(A23.y, off);
        }
        if (g == 0) {
            float rv = 1.f / (wself + wsum + 1e-16f);
            float4 bv = *reinterpret_cast<const float4*>(&bias[l16 << 2]);
            o.x = A01.x * rv + bv.x; o.y = A01.y * rv + bv.y;
            o.z = A23.x * rv + bv.z; o.w = A23.y * rv + bv.w;
            *reinterpret_cast<float4*>(&out[(size_t)wv * 64 + (l16 << 2)]) = o;
        }
    }
    if (g == 0)
        *reinterpret_cast<float4*>(&stage[w][l16 << 2]) = o;
    __syncthreads();
    int tid = threadIdx.x;
    if (tid < 64) {
        float s = 0.f, s2 = 0.f;
        #pragma unroll
        for (int k = 0; k < 4; k++) {
            float v = stage[k][tid];
            s += v; s2 += v * v;
        }
        float* dst = ostats + (blockIdx.x & (NCOPY - 1)) * 128;
        atomicAdd(&dst[tid], s);
        atomicAdd(&dst[64 + tid], s2);
    }
}

// ---------------- final head: relu(bn(h)) @ lw2 + lb2 ----------------
__global__ void k_head(const float* __restrict__ h, const float* __restrict__ bnst,
                       float invN,
                       const float* __restrict__ lw2, const float* __restrict__ lb2,
                       float* __restrict__ out, int n)
{
    __shared__ float muH[64], rsH[64];
    int tid = threadIdx.x;
    if (tid < 64) {
        float s = 0.f, s2 = 0.f;
        #pragma unroll
        for (int c = 0; c < NCOPY; c++) {
            s  += bnst[c * 128 + tid];
            s2 += bnst[c * 128 + 64 + tid];
        }
        float m = s * invN;
        float var = s2 * invN - m * m;
        muH[tid] = m;
        rsH[tid] = rsqrtf(var + EPS_BN);
    }
    __syncthreads();
    int wv = (blockIdx.x * blockDim.x + threadIdx.x) >> 6;
    int lane = threadIdx.x & 63;
    if (wv >= n) return;
    float v = fmaxf((h[(size_t)wv * 64 + lane] - muH[lane]) * rsH[lane], 0.f);
    float c0 = v * lw2[lane * 2 + 0];
    float c1 = v * lw2[lane * 2 + 1];
    #pragma unroll
    for (int off = 32; off; off >>= 1) {
        c0 += __shfl_xor(c0, off);
        c1 += __shfl_xor(c1, off);
    }
    if (lane == 0) {
        out[wv * 2 + 0] = c0 + lb2[0];
        out[wv * 2 + 1] = c1 + lb2[1];
    }
}

extern "C" void kernel_launch(void* const* d_in, const int* in_sizes, int n_in,
                              void* d_out, int out_size, void* d_ws, size_t ws_size,
                              hipStream_t stream)
{
    const float* x   = (const float*)d_in[0];
    const int*   ei  = (const int*)d_in[1];
    const float* W0  = (const float*)d_in[2];
    const float* as0 = (const float*)d_in[3];
    const float* ad0 = (const float*)d_in[4];
    const float* b0  = (const float*)d_in[5];
    const float* W1  = (const float*)d_in[6];
    const float* as1 = (const float*)d_in[7];
    const float* ad1 = (const float*)d_in[8];
    const float* b1  = (const float*)d_in[9];
    const float* W2  = (const float*)d_in[10];
    const float* as2 = (const float*)d_in[11];
    const float* ad2 = (const float*)d_in[12];
    const float* b2  = (const float*)d_in[13];
    const float* lw1 = (const float*)d_in[14];
    const float* lb1 = (const float*)d_in[15];
    const float* lw2 = (const float*)d_in[16];
    const float* lb2 = (const float*)d_in[17];
    float* out = (float*)d_out;

    const int n = in_sizes[0] / F_IN;   // 50000
    const int e = in_sizes[1] / 2;      // 800000
    const int nbin = (n + 255) >> 8;    // 196

    char* ws = (char*)d_ws;
    size_t off = 0;
    auto alloc = [&](size_t bytes) -> void* {
        void* p = ws + off;
        off += (bytes + 255) & ~(size_t)255;
        return p;
    };
    unsigned short* aggx = (unsigned short*)alloc((size_t)n * 512 * 2);     // 51.2 MB
    unsigned short* Hb   = aggx;                                            // layers 1/2 gather buf
    unsigned int*   SE   = (unsigned int*)aggx;                             // sorted edges (dead before aggx4)
    unsigned short* out0b = (unsigned short*)alloc((size_t)n * 256 * 2);    // 25.6 MB
    int* H  = (int*)out0b;                                                  // hist (dead before gemm_bd)
    int* Hc = (int*)(out0b + 512 * 1024);                                   // scan
    float* B64 = (float*)alloc((size_t)n * 64 * 4);                         // 12.8 MB
    unsigned short* xb = (unsigned short*)alloc((size_t)(n + 1) * 128 * 2); // 12.8 MB (+dummy row)
    float* g3 = (float*)xb;
    float* a_src = (float*)alloc(((size_t)n * 4 + 8) * 4);
    float* a_dst = (float*)alloc((size_t)n * 4 * 4);
    unsigned short* Wt0 = (unsigned short*)alloc(256 * 128 * 2);
    unsigned short* Wt1 = (unsigned short*)alloc(64 * 256 * 2);
    unsigned short* Wt2 = (unsigned short*)alloc(64 * 64 * 2);
    unsigned short* Wtm = (unsigned short*)alloc(64 * 64 * 2);
    float* vsd  = (float*)alloc(1024 * 4);
    int* col    = (int*)alloc(((size_t)e + 8 * (size_t)n) * 4);             // padded CSR
    int* startp = (int*)alloc((size_t)n * 4);
    int* deg    = (int*)alloc((size_t)n * 4);
    int* bintot = (int*)alloc(512 * 4);
    int* SEbase = (int*)alloc(512 * 4);
    int* binpad = (int*)alloc(512 * 4);
    int* binbase = (int*)alloc(512 * 4);
    char* zbase = ws + off;
    float* st0 = (float*)alloc(NCOPY * 512 * 4);
    float* st1 = (float*)alloc(NCOPY * 128 * 4);
    float* st2 = (float*)alloc(NCOPY * 128 * 4);
    float* st3 = (float*)alloc(NCOPY * 128 * 4);
    size_t zsize = (size_t)((ws + off) - zbase);

    const float invN = 1.f / (float)n;

    hipMemsetAsync(zbase, 0, zsize, stream);

    const int tpb = 256;
    k_wprep_all<<<229, tpb, 0, stream>>>(W0, W1, W2, lw1, as0, ad0, Wt0, Wt1, Wt2, Wtm,
                                         vsd, a_src, n);

    const int wgrid = (n + 3) / 4;   // 12500 blocks (>= NBLK)
    // fused hist + layer-0 prep
    k_front<<<wgrid, tpb, 0, stream>>>(ei, e, nbin, H, x, vsd, xb, a_src, a_dst, n);

    // ---- rest of CSR build (counting sort; no device atomics; parallel scans) ----
    k_scanbins<<<(nbin * 64 + tpb - 1) / tpb, tpb, 0, stream>>>(H, Hc, bintot, nbin);
    k_scanbase<<<1, tpb, 0, stream>>>(bintot, SEbase, nbin);
    k_scatter<<<NBLK, tpb, 0, stream>>>(ei, e, Hc, SEbase, SE, nbin);
    k_degb<<<nbin, tpb, 0, stream>>>(SE, SEbase, deg, binpad, n);
    k_binscan<<<1, tpb, 0, stream>>>(binpad, binbase, nbin);
    k_fillb<<<nbin, tpb, 0, stream>>>(SE, SEbase, binbase, deg, col, startp, n);

    const int rowTiles = (n + 63) / 64;

    // Layer 0: x-aggregate (8-edge, packed fp32) -> block-diagonal GEMM
    k_aggx4<<<wgrid, 256, 0, stream>>>(xb, a_src, a_dst, startp, deg, col, aggx, n);
    k_gemm_bd<<<dim3(rowTiles, 4), 256, 0, stream>>>(aggx, Wt0, b0, out0b, st0, n);

    // Layer 1: GAT 256 -> 64 (bf16 A, BN fused from st0); Hb aliases aggx (dead)
    k_gemm<true, true, true><<<dim3(rowTiles, 1), 256, 0, stream>>>(
        nullptr, out0b, Wt1, nullptr, st0, invN, as1, ad1, a_src, a_dst, 1,
        nullptr, Hb, nullptr, n, 256, 64);
    k_agg1f<<<wgrid, 256, 0, stream>>>(Hb, a_src, a_dst, startp, deg, col, b1, B64, st1, n);

    // Layer 2: GAT 64 -> 64 (fp32 A from B64)
    k_gemm<true, true, false><<<dim3(rowTiles, 1), 256, 0, stream>>>(
        B64, nullptr, Wt2, nullptr, st1, invN, as2, ad2, a_src, a_dst, 1,
        nullptr, Hb, nullptr, n, 64, 64);
    k_agg1f<<<wgrid, 256, 0, stream>>>(Hb, a_src, a_dst, startp, deg, col, b2, B64, st2, n);

    // MLP: relu(bn(out2)) @ lw1 + lb1 -> g3 (aliases xb, dead); stats st3
    k_gemm<true, false, false><<<dim3(rowTiles, 1), 256, 0, stream>>>(
        B64, nullptr, Wtm, lb1, st2, invN, nullptr, nullptr, nullptr, nullptr, 1,
        g3, nullptr, st3, n, 64, 64);

    // head: relu(bn(g3)) @ lw2 + lb2
    k_head<<<wgrid, 256, 0, stream>>>(g3, st3, invN, lw2, lb2, out, n);
}

// Round 18
// 269.003 us; speedup vs baseline: 1.0085x; 1.0085x over previous
//
#include <hip/hip_runtime.h>

#define F_IN 128
#define EPS_BN 1e-5f
#define NCOPY 8
#define NBLK 256          // sort blocks (64B runs per (bin,blk): full cache line)

typedef __attribute__((ext_vector_type(8))) short short8v;
typedef __attribute__((ext_vector_type(4))) float f32x4;
typedef __attribute__((ext_vector_type(2))) float f32x2;

__device__ __forceinline__ float lrelu(float x) { return x >= 0.f ? x : 0.2f * x; }
__device__ __forceinline__ unsigned short f2bf(float f) {
    unsigned int u = __float_as_uint(f);
    u += 0x7FFFu + ((u >> 16) & 1u);
    return (unsigned short)(u >> 16);
}
__device__ __forceinline__ float bf2f(unsigned short s) {
    return __uint_as_float(((unsigned int)s) << 16);
}
// unpack a uint holding 2 bf16 (lo=ch0, hi=ch1) into float2 — 2 VALU ops
__device__ __forceinline__ f32x2 bfpair(unsigned int u) {
    f32x2 r;
    r.x = __uint_as_float(u << 16);
    r.y = __uint_as_float(u & 0xFFFF0000u);
    return r;
}

// ================= CSR build via two-level counting sort (no device atomics) =================

// fused: per-block histogram (blocks < NBLK) + layer-0 prep (wave per node, all blocks)
__global__ void k_front(const int* __restrict__ ei, int e, int nbin, int* __restrict__ H,
                        const float* __restrict__ x, const float* __restrict__ vsd,
                        unsigned short* __restrict__ xb,
                        float* __restrict__ a_src, float* __restrict__ a_dst, int n)
{
    __shared__ int hist[256];
    int blk = blockIdx.x, tid = threadIdx.x;
    if (blk < NBLK) {
        if (tid < nbin) hist[tid] = 0;
        __syncthreads();
        int per = (e + NBLK - 1) / NBLK;
        int t0 = blk * per, t1 = min(t0 + per, e);
        for (int t = t0 + tid; t < t1; t += 256)
            atomicAdd(&hist[ei[e + t] >> 8], 1);
        __syncthreads();
        if (tid < nbin) H[tid * NBLK + blk] = hist[tid];
    }
    // prep0: wave per node
    int wv = (blk * blockDim.x + tid) >> 6;
    int lane = tid & 63;
    if (wv >= n) return;
    const int xo = lane << 1;
    float2 xv = *reinterpret_cast<const float2*>(&x[(size_t)wv * 128 + xo]);
    ushort2 o;
    o.x = f2bf(xv.x); o.y = f2bf(xv.y);
    *reinterpret_cast<ushort2*>(&xb[(size_t)wv * 128 + xo]) = o;
    float ps[4], pd[4];
    #pragma unroll
    for (int h = 0; h < 4; h++) {
        float2 v2 = *reinterpret_cast<const float2*>(&vsd[h * 128 + xo]);
        float2 w2 = *reinterpret_cast<const float2*>(&vsd[512 + h * 128 + xo]);
        ps[h] = xv.x * v2.x + xv.y * v2.y;
        pd[h] = xv.x * w2.x + xv.y * w2.y;
    }
    #pragma unroll
    for (int off = 32; off; off >>= 1) {
        #pragma unroll
        for (int h = 0; h < 4; h++) {
            ps[h] += __shfl_xor(ps[h], off);
            pd[h] += __shfl_xor(pd[h], off);
        }
    }
    if (lane == 0) {
        *reinterpret_cast<float4*>(&a_src[wv * 4]) = make_float4(ps[0], ps[1], ps[2], ps[3]);
        *reinterpret_cast<float4*>(&a_dst[wv * 4]) = make_float4(pd[0], pd[1], pd[2], pd[3]);
    }
}

__global__ void k_scanbins(const int* __restrict__ H, int* __restrict__ Hc,
                           int* __restrict__ bintot, int nbin) {
    int wv = (blockIdx.x * blockDim.x + threadIdx.x) >> 6;
    int lane = threadIdx.x & 63;
    if (wv >= nbin) return;
    int carry = 0;
    for (int c = 0; c < NBLK; c += 64) {
        int v = H[wv * NBLK + c + lane];
        int s = v;
        #pragma unroll
        for (int off = 1; off < 64; off <<= 1) {
            int u = __shfl_up(s, off);
            if (lane >= off) s += u;
        }
        Hc[wv * NBLK + c + lane] = carry + s - v;   // exclusive
        carry += __shfl(s, 63);
    }
    if (lane == 0) bintot[wv] = carry;
}

__global__ void k_scanbase(const int* __restrict__ bintot, int* __restrict__ SEbase, int nbin) {
    __shared__ int buf[256];
    int tid = threadIdx.x;
    if (tid < nbin) buf[tid] = bintot[tid];
    __syncthreads();
    if (tid == 0) {
        int run = 0;
        for (int b = 0; b < nbin; b++) { SEbase[b] = run; run += buf[b]; }
        SEbase[nbin] = run;
    }
}

__global__ void k_scatter(const int* __restrict__ ei, int e, const int* __restrict__ Hc,
                          const int* __restrict__ SEbase, unsigned int* __restrict__ SE, int nbin) {
    __shared__ int cur[256];
    int blk = blockIdx.x, tid = threadIdx.x;
    if (tid < nbin) cur[tid] = SEbase[tid] + Hc[tid * NBLK + blk];
    __syncthreads();
    int per = (e + NBLK - 1) / NBLK;
    int t0 = blk * per, t1 = min(t0 + per, e);
    for (int t = t0 + tid; t < t1; t += 256) {
        int s = ei[t], d = ei[e + t];
        int pos = atomicAdd(&cur[d >> 8], 1);     // LDS atomic (block-local)
        SE[pos] = ((unsigned int)d << 16) | (unsigned int)s;
    }
}

__global__ void k_degb(const unsigned int* __restrict__ SE, const int* __restrict__ SEbase,
                       int* __restrict__ deg, int* __restrict__ binpad, int n) {
    __shared__ int hist[256];
    __shared__ int red[256];
    int b = blockIdx.x, tid = threadIdx.x;
    hist[tid] = 0;
    __syncthreads();
    int t0 = SEbase[b], t1 = SEbase[b + 1];
    for (int t = t0 + tid; t < t1; t += 256)
        atomicAdd(&hist[(int)(SE[t] >> 16) - (b << 8)], 1);
    __syncthreads();
    int dst = (b << 8) + tid;
    int dv = hist[tid];
    if (dst < n) deg[dst] = dv;
    red[tid] = (dst < n) ? ((dv + 7) & ~7) : 0;
    __syncthreads();
    #pragma unroll
    for (int s = 128; s; s >>= 1) {
        if (tid < s) red[tid] += red[tid + s];
        __syncthreads();
    }
    if (tid == 0) binpad[b] = red[0];
}

__global__ void k_binscan(const int* __restrict__ binpad, int* __restrict__ binbase, int nbin) {
    __shared__ int buf[256];
    int tid = threadIdx.x;
    int pv = (tid < nbin) ? binpad[tid] : 0;
    buf[tid] = pv;
    __syncthreads();
    for (int off = 1; off < 256; off <<= 1) {
        int v = (tid >= off) ? buf[tid - off] : 0;
        __syncthreads();
        buf[tid] += v;
        __syncthreads();
    }
    if (tid < nbin) binbase[tid] = buf[tid] - pv;   // exclusive
}

__global__ void k_fillb(const unsigned int* __restrict__ SE, const int* __restrict__ SEbase,
                        const int* __restrict__ binbase, const int* __restrict__ deg,
                        int* __restrict__ col, int* __restrict__ startp, int n) {
    __shared__ int sps[256];
    __shared__ int cur[256];
    int b = blockIdx.x, tid = threadIdx.x;
    int dst = (b << 8) + tid;
    int pv = (dst < n) ? ((deg[dst] + 7) & ~7) : 0;
    sps[tid] = pv;
    __syncthreads();
    for (int off = 1; off < 256; off <<= 1) {
        int v = (tid >= off) ? sps[tid - off] : 0;
        __syncthreads();
        sps[tid] += v;
        __syncthreads();
    }
    int sp = binbase[b] + sps[tid] - pv;   // exclusive
    if (dst < n) startp[dst] = sp;
    cur[tid] = sp;
    __syncthreads();
    int t0 = SEbase[b], t1 = SEbase[b + 1];
    for (int t = t0 + tid; t < t1; t += 256) {
        unsigned int se = SE[t];
        int pos = atomicAdd(&cur[(int)(se >> 16) - (b << 8)], 1);   // LDS atomic
        col[pos] = (int)(se & 0xFFFFu);
    }
    __syncthreads();
    if (dst < n) {
        int p = cur[tid];                                   // = sp + deg
        int pe = sp + pv;
        for (; p < pe; p++) col[p] = n;
    }
}

// ---------------- weight prep + layer-0 score vectors + dummy score slot ----------------
__global__ void k_wprep_all(const float* __restrict__ W0, const float* __restrict__ W1,
                            const float* __restrict__ W2, const float* __restrict__ lw1,
                            const float* __restrict__ as0, const float* __restrict__ ad0,
                            unsigned short* __restrict__ Wt0, unsigned short* __restrict__ Wt1,
                            unsigned short* __restrict__ Wt2, unsigned short* __restrict__ Wtm,
                            float* __restrict__ vsd, float* __restrict__ a_src, int n)
{
    int t = blockIdx.x * blockDim.x + threadIdx.x;
    if (t < 32768) {               // W0: K=128, Nc=256
        int nn = t / 128, kk = t - nn * 128;
        Wt0[t] = f2bf(W0[(size_t)kk * 256 + nn]);
    } else if (t < 49152) {        // W1: K=256, Nc=64
        int u = t - 32768;
        int nn = u / 256, kk = u - nn * 256;
        Wt1[u] = f2bf(W1[(size_t)kk * 64 + nn]);
    } else if (t < 53248) {        // W2: K=64, Nc=64
        int u = t - 49152;
        int nn = u / 64, kk = u - nn * 64;
        Wt2[u] = f2bf(W2[(size_t)kk * 64 + nn]);
    } else if (t < 57344) {        // lw1: K=64, Nc=64
        int u = t - 53248;
        int nn = u / 64, kk = u - nn * 64;
        Wtm[u] = f2bf(lw1[(size_t)kk * 64 + nn]);
    } else if (t < 57856) {        // vs[h][k]
        int u = t - 57344;
        int h = u >> 7, k = u & 127;
        float s = 0.f;
        for (int d2 = 0; d2 < 64; d2++) s += W0[(size_t)k * 256 + h * 64 + d2] * as0[h * 64 + d2];
        vsd[u] = s;
    } else if (t < 58368) {        // vd[h][k]
        int u = t - 57856;
        int h = u >> 7, k = u & 127;
        float s = 0.f;
        for (int d2 = 0; d2 < 64; d2++) s += W0[(size_t)k * 256 + h * 64 + d2] * ad0[h * 64 + d2];
        vsd[512 + u] = s;
    } else if (t < 58372) {        // dummy-node H=4 score slot: exp(-inf)=0
        a_src[4 * n + (t - 58368)] = -1e30f;
    }
}

// ---------------- layer-0 aggregation over x: 8 edges/iter, packed-fp32 accumulate ----------------
__global__ void k_aggx4(const unsigned short* __restrict__ xb,
                        const float* __restrict__ asrc, const float* __restrict__ adst,
                        const int* __restrict__ startp, const int* __restrict__ deg,
                        const int* __restrict__ col,
                        unsigned short* __restrict__ aggx, int n)
{
    __shared__ float lds_w[4][64];
    int wv = (blockIdx.x * blockDim.x + threadIdx.x) >> 6;
    int lane = threadIdx.x & 63;
    int wid = threadIdx.x >> 6;
    if (wv >= n) return;
    const int s0 = startp[wv], d = deg[wv];
    const int dpad = (d + 7) & ~7;
    const int eslot = (lane & 31) >> 2;
    const int hslot = lane & 3;
    const float4 adh4 = *reinterpret_cast<const float4*>(&adst[wv * 4]);
    const float4 asf4 = *reinterpret_cast<const float4*>(&asrc[wv * 4]);
    const float adh_h = hslot == 0 ? adh4.x : hslot == 1 ? adh4.y :
                        hslot == 2 ? adh4.z : adh4.w;
    const float w0 = __expf(lrelu(asf4.x + adh4.x));
    const float w1 = __expf(lrelu(asf4.y + adh4.y));
    const float w2 = __expf(lrelu(asf4.z + adh4.z));
    const float w3 = __expf(lrelu(asf4.w + adh4.w));
    const unsigned int* xbu = reinterpret_cast<const unsigned int*>(xb);  // 64 uints/row
    f32x2 xv = bfpair(xbu[(size_t)wv * 64 + lane]);
    f32x2 A0 = w0 * xv, A1 = w1 * xv, A2 = w2 * xv, A3 = w3 * xv;
    float wsum = 0.f;
    const int* crow = col + s0;
    const float* asrcp = asrc + hslot;
    for (int t = 0; t < dpad; t += 8) {
        int se = crow[t + eslot];
        float wme = __expf(lrelu(asrcp[se * 4] + adh_h));
        wsum += wme;
        lds_w[wid][lane] = wme;
        int4 c0 = *reinterpret_cast<const int4*>(&crow[t]);
        int4 c1 = *reinterpret_cast<const int4*>(&crow[t + 4]);
        f32x2 xA = bfpair(xbu[(size_t)c0.x * 64 + lane]);
        f32x2 xB = bfpair(xbu[(size_t)c0.y * 64 + lane]);
        f32x2 xC = bfpair(xbu[(size_t)c0.z * 64 + lane]);
        f32x2 xD = bfpair(xbu[(size_t)c0.w * 64 + lane]);
        f32x2 xE = bfpair(xbu[(size_t)c1.x * 64 + lane]);
        f32x2 xF = bfpair(xbu[(size_t)c1.y * 64 + lane]);
        f32x2 xG = bfpair(xbu[(size_t)c1.z * 64 + lane]);
        f32x2 xH = bfpair(xbu[(size_t)c1.w * 64 + lane]);
        float4 wA = *reinterpret_cast<const float4*>(&lds_w[wid][0]);
        float4 wB = *reinterpret_cast<const float4*>(&lds_w[wid][4]);
        float4 wC = *reinterpret_cast<const float4*>(&lds_w[wid][8]);
        float4 wD = *reinterpret_cast<const float4*>(&lds_w[wid][12]);
        float4 wE = *reinterpret_cast<const float4*>(&lds_w[wid][16]);
        float4 wF = *reinterpret_cast<const float4*>(&lds_w[wid][20]);
        float4 wG = *reinterpret_cast<const float4*>(&lds_w[wid][24]);
        float4 wH = *reinterpret_cast<const float4*>(&lds_w[wid][28]);
        A0 += wA.x * xA; A0 += wB.x * xB; A0 += wC.x * xC; A0 += wD.x * xD;
        A0 += wE.x * xE; A0 += wF.x * xF; A0 += wG.x * xG; A0 += wH.x * xH;
        A1 += wA.y * xA; A1 += wB.y * xB; A1 += wC.y * xC; A1 += wD.y * xD;
        A1 += wE.y * xE; A1 += wF.y * xF; A1 += wG.y * xG; A1 += wH.y * xH;
        A2 += wA.z * xA; A2 += wB.z * xB; A2 += wC.z * xC; A2 += wD.z * xD;
        A2 += wE.z * xE; A2 += wF.z * xF; A2 += wG.z * xG; A2 += wH.z * xH;
        A3 += wA.w * xA; A3 += wB.w * xB; A3 += wC.w * xC; A3 += wD.w * xD;
        A3 += wE.w * xE; A3 += wF.w * xF; A3 += wG.w * xG; A3 += wH.w * xH;
    }
    wsum += __shfl_xor(wsum, 4);
    wsum += __shfl_xor(wsum, 8);
    wsum += __shfl_xor(wsum, 16);
    float r0 = 1.f / (w0 + __shfl(wsum, 0) + 1e-16f);
    float r1 = 1.f / (w1 + __shfl(wsum, 1) + 1e-16f);
    float r2 = 1.f / (w2 + __shfl(wsum, 2) + 1e-16f);
    float r3 = 1.f / (w3 + __shfl(wsum, 3) + 1e-16f);
    const int xo = lane << 1;
    size_t base = (size_t)wv * 512 + xo;
    ushort2 o;
    o.x = f2bf(A0.x * r0); o.y = f2bf(A0.y * r0);
    *reinterpret_cast<ushort2*>(&aggx[base]) = o;
    o.x = f2bf(A1.x * r1); o.y = f2bf(A1.y * r1);
    *reinterpret_cast<ushort2*>(&aggx[base + 128]) = o;
    o.x = f2bf(A2.x * r2); o.y = f2bf(A2.y * r2);
    *reinterpret_cast<ushort2*>(&aggx[base + 256]) = o;
    o.x = f2bf(A3.x * r3); o.y = f2bf(A3.y * r3);
    *reinterpret_cast<ushort2*>(&aggx[base + 384]) = o;
}

// ---------------- layer-0 block-diagonal GEMM: out0b = bf16(aggx_bd @ W0 + b0) ----------------
__global__ __launch_bounds__(256) void k_gemm_bd(
    const unsigned short* __restrict__ Ab, const unsigned short* __restrict__ Wt,
    const float* __restrict__ bias, unsigned short* __restrict__ Cb0,
    float* __restrict__ ostats, int M)
{
    __shared__ unsigned short As[64 * 136];
    __shared__ unsigned short Bs[64 * 136];
    __shared__ float sred[4][4][16], sred2[4][4][16];
    const int tid = threadIdx.x;
    const int w = tid >> 6, lane = tid & 63;
    const int l15 = lane & 15, g = lane >> 4;
    const int bm = blockIdx.x * 64, bn = blockIdx.y * 64;
    const int hh = blockIdx.y;
    const int srow = tid >> 2;
    const int sk = (tid & 3) << 5;

    {
        short8v a0, a1, a2, a3;
        if (bm + srow < M) {
            const unsigned short* ap = &Ab[(size_t)(bm + srow) * 512 + hh * 128 + sk];
            a0 = *reinterpret_cast<const short8v*>(ap);
            a1 = *reinterpret_cast<const short8v*>(ap + 8);
            a2 = *reinterpret_cast<const short8v*>(ap + 16);
            a3 = *reinterpret_cast<const short8v*>(ap + 24);
        } else {
            a0 = a1 = a2 = a3 = (short8v){0,0,0,0,0,0,0,0};
        }
        const unsigned short* bp = &Wt[(size_t)(bn + srow) * 128 + sk];
        short8v b0v = *reinterpret_cast<const short8v*>(bp);
        short8v b1v = *reinterpret_cast<const short8v*>(bp + 8);
        short8v b2v = *reinterpret_cast<const short8v*>(bp + 16);
        short8v b3v = *reinterpret_cast<const short8v*>(bp + 24);
        unsigned short* arow = &As[srow * 136 + sk];
        *reinterpret_cast<short8v*>(arow) = a0;
        *reinterpret_cast<short8v*>(arow + 8) = a1;
        *reinterpret_cast<short8v*>(arow + 16) = a2;
        *reinterpret_cast<short8v*>(arow + 24) = a3;
        unsigned short* brow = &Bs[srow * 136 + sk];
        *reinterpret_cast<short8v*>(brow) = b0v;
        *reinterpret_cast<short8v*>(brow + 8) = b1v;
        *reinterpret_cast<short8v*>(brow + 16) = b2v;
        *reinterpret_cast<short8v*>(brow + 24) = b3v;
    }
    __syncthreads();

    f32x4 acc[4];
    #pragma unroll
    for (int nt = 0; nt < 4; nt++) acc[nt] = (f32x4){0.f, 0.f, 0.f, 0.f};
    #pragma unroll
    for (int kk = 0; kk < 4; kk++) {
        short8v af = *reinterpret_cast<const short8v*>(&As[(w * 16 + l15) * 136 + kk * 32 + g * 8]);
        #pragma unroll
        for (int nt = 0; nt < 4; nt++) {
            short8v bf = *reinterpret_cast<const short8v*>(&Bs[(nt * 16 + l15) * 136 + kk * 32 + g * 8]);
            acc[nt] = __builtin_amdgcn_mfma_f32_16x16x32_bf16(af, bf, acc[nt], 0, 0, 0);
        }
    }

    float s[4] = {0.f, 0.f, 0.f, 0.f}, s2[4] = {0.f, 0.f, 0.f, 0.f};
    #pragma unroll
    for (int reg = 0; reg < 4; reg++) {
        int row = bm + w * 16 + g * 4 + reg;
        if (row < M) {
            #pragma unroll
            for (int nt = 0; nt < 4; nt++) {
                float v = acc[nt][reg] + bias[bn + nt * 16 + l15];
                Cb0[(size_t)row * 256 + bn + nt * 16 + l15] = f2bf(v);
                s[nt] += v; s2[nt] += v * v;
            }
        }
    }
    #pragma unroll
    for (int off = 16; off <= 32; off <<= 1) {
        #pragma unroll
        for (int nt = 0; nt < 4; nt++) {
            s[nt]  += __shfl_xor(s[nt], off);
            s2[nt] += __shfl_xor(s2[nt], off);
        }
    }
    if (g == 0) {
        #pragma unroll
        for (int nt = 0; nt < 4; nt++) { sred[w][nt][l15] = s[nt]; sred2[w][nt][l15] = s2[nt]; }
    }
    __syncthreads();
    if (tid < 64) {
        int nt = tid >> 4, c = tid & 15;
        float S = 0.f, S2 = 0.f;
        #pragma unroll
        for (int w4 = 0; w4 < 4; w4++) { S += sred[w4][nt][c]; S2 += sred2[w4][nt][c]; }
        float* dst = ostats + (blockIdx.x & (NCOPY - 1)) * 512 + bn;
        atomicAdd(&dst[tid], S);
        atomicAdd(&dst[256 + tid], S2);
    }
}

// ---------------- bf16 MFMA GEMM (layers 1,2, MLP) ----------------
template<bool BN, bool ATT, bool AB16>
__global__ __launch_bounds__(256) void k_gemm(
    const float* __restrict__ Af, const unsigned short* __restrict__ Abf,
    const unsigned short* __restrict__ Wt,
    const float* __restrict__ bias,
    const float* __restrict__ bnst, float invN,
    const float* __restrict__ att_s, const float* __restrict__ att_d,
    float* __restrict__ a_src, float* __restrict__ a_dst, int H,
    float* __restrict__ Cf, unsigned short* __restrict__ Cb,
    float* __restrict__ ostats,
    int M, int K, int Nc)
{
    __shared__ unsigned short As[64 * 40];
    __shared__ unsigned short Bs[64 * 40];
    __shared__ float muS[256], rsS[256];
    const int tid = threadIdx.x;
    const int w = tid >> 6, lane = tid & 63;
    const int l15 = lane & 15, g = lane >> 4;
    const int bm = blockIdx.x * 64, bn = blockIdx.y * 64;
    const int srow = tid >> 2;
    const int skq  = (tid & 3) << 3;

    if constexpr (BN) {
        if (tid < K) {
            float s = 0.f, s2 = 0.f;
            #pragma unroll
            for (int c = 0; c < NCOPY; c++) {
                s  += bnst[c * 2 * K + tid];
                s2 += bnst[c * 2 * K + K + tid];
            }
            float m = s * invN;
            float var = s2 * invN - m * m;
            muS[tid] = m;
            rsS[tid] = rsqrtf(var + EPS_BN);
        }
        __syncthreads();
    }

    f32x4 acc[4];
    #pragma unroll
    for (int nt = 0; nt < 4; nt++) acc[nt] = (f32x4){0.f, 0.f, 0.f, 0.f};

    for (int k0 = 0; k0 < K; k0 += 32) {
        short8v a8;
        if (bm + srow < M) {
            if constexpr (AB16) {
                short8v u = *reinterpret_cast<const short8v*>(&Abf[(size_t)(bm + srow) * K + k0 + skq]);
                if constexpr (BN) {
                    #pragma unroll
                    for (int j = 0; j < 8; j++) {
                        int kb = k0 + skq + j;
                        float f = bf2f((unsigned short)u[j]);
                        f = fmaxf((f - muS[kb]) * rsS[kb], 0.f);
                        a8[j] = (short)f2bf(f);
                    }
                } else {
                    a8 = u;
                }
            } else {
                const float* ap = &Af[(size_t)(bm + srow) * K + k0 + skq];
                float4 v0 = *reinterpret_cast<const float4*>(ap);
                float4 v1 = *reinterpret_cast<const float4*>(ap + 4);
                if constexpr (BN) {
                    int kb = k0 + skq;
                    v0.x = fmaxf((v0.x - muS[kb + 0]) * rsS[kb + 0], 0.f);
                    v0.y = fmaxf((v0.y - muS[kb + 1]) * rsS[kb + 1], 0.f);
                    v0.z = fmaxf((v0.z - muS[kb + 2]) * rsS[kb + 2], 0.f);
                    v0.w = fmaxf((v0.w - muS[kb + 3]) * rsS[kb + 3], 0.f);
                    v1.x = fmaxf((v1.x - muS[kb + 4]) * rsS[kb + 4], 0.f);
                    v1.y = fmaxf((v1.y - muS[kb + 5]) * rsS[kb + 5], 0.f);
                    v1.z = fmaxf((v1.z - muS[kb + 6]) * rsS[kb + 6], 0.f);
                    v1.w = fmaxf((v1.w - muS[kb + 7]) * rsS[kb + 7], 0.f);
                }
                a8[0] = (short)f2bf(v0.x); a8[1] = (short)f2bf(v0.y);
                a8[2] = (short)f2bf(v0.z); a8[3] = (short)f2bf(v0.w);
                a8[4] = (short)f2bf(v1.x); a8[5] = (short)f2bf(v1.y);
                a8[6] = (short)f2bf(v1.z); a8[7] = (short)f2bf(v1.w);
            }
        } else {
            a8 = (short8v){0,0,0,0,0,0,0,0};
        }
        short8v b8 = *reinterpret_cast<const short8v*>(&Wt[(size_t)(bn + srow) * K + k0 + skq]);
        __syncthreads();
        *reinterpret_cast<short8v*>(&As[srow * 40 + skq]) = a8;
        *reinterpret_cast<short8v*>(&Bs[srow * 40 + skq]) = b8;
        __syncthreads();
        short8v af = *reinterpret_cast<const short8v*>(&As[(w * 16 + l15) * 40 + g * 8]);
        #pragma unroll
        for (int nt = 0; nt < 4; nt++) {
            short8v bf = *reinterpret_cast<const short8v*>(&Bs[(nt * 16 + l15) * 40 + g * 8]);
            acc[nt] = __builtin_amdgcn_mfma_f32_16x16x32_bf16(af, bf, acc[nt], 0, 0, 0);
        }
    }

    if constexpr (ATT) {
        float wsv[4], wdv[4];
        #pragma unroll
        for (int nt = 0; nt < 4; nt++) {
            wsv[nt] = att_s[bn + nt * 16 + l15];
            wdv[nt] = att_d[bn + nt * 16 + l15];
        }
        #pragma unroll
        for (int reg = 0; reg < 4; reg++) {
            int row = bm + w * 16 + g * 4 + reg;
            float ps = 0.f, pd = 0.f;
            #pragma unroll
            for (int nt = 0; nt < 4; nt++) {
                float c = acc[nt][reg];
                ps += c * wsv[nt];
                pd += c * wdv[nt];
                if (row < M)
                    Cb[(size_t)row * Nc + bn + nt * 16 + l15] = f2bf(c);
            }
            #pragma unroll
            for (int off = 1; off < 16; off <<= 1) {
                ps += __shfl_xor(ps, off);
                pd += __shfl_xor(pd, off);
            }
            if (l15 == 0 && row < M) {
                int hh = bn >> 6;
                a_src[(size_t)row * H + hh] = ps;
                a_dst[(size_t)row * H + hh] = pd;
            }
        }
        // dummy slot for padded-CSR aggregation (H=1 layers): weight -> 0
        if (H == 1 && blockIdx.x == 0 && blockIdx.y == 0 && tid == 0)
            a_src[M] = -1e30f;
    } else {
        __shared__ float sred[4][4][16], sred2[4][4][16];
        float s[4] = {0.f, 0.f, 0.f, 0.f}, s2[4] = {0.f, 0.f, 0.f, 0.f};
        #pragma unroll
        for (int reg = 0; reg < 4; reg++) {
            int row = bm + w * 16 + g * 4 + reg;
            if (row < M) {
                #pragma unroll
                for (int nt = 0; nt < 4; nt++) {
                    float v = acc[nt][reg] + bias[bn + nt * 16 + l15];
                    Cf[(size_t)row * Nc + bn + nt * 16 + l15] = v;
                    s[nt] += v; s2[nt] += v * v;
                }
            }
        }
        #pragma unroll
        for (int off = 16; off <= 32; off <<= 1) {
            #pragma unroll
            for (int nt = 0; nt < 4; nt++) {
                s[nt]  += __shfl_xor(s[nt], off);
                s2[nt] += __shfl_xor(s2[nt], off);
            }
        }
        if (g == 0) {
            #pragma unroll
            for (int nt = 0; nt < 4; nt++) { sred[w][nt][l15] = s[nt]; sred2[w][nt][l15] = s2[nt]; }
        }
        __syncthreads();
        if (tid < 64) {
            int nt = tid >> 4, c = tid & 15;
            float S = 0.f, S2 = 0.f;
            #pragma unroll
            for (int w4 = 0; w4 < 4; w4++) { S += sred[w4][nt][c]; S2 += sred2[w4][nt][c]; }
            float* dst = ostats + (blockIdx.x & (NCOPY - 1)) * 128;
            atomicAdd(&dst[tid], S);
            atomicAdd(&dst[64 + tid], S2);
        }
    }
}

// ---------------- fused softmax aggregation + BN stats, H=1 (4 groups x 16 lanes, padded) ----------------
__global__ void k_agg1f(const unsigned short* __restrict__ hb,
                        const float* __restrict__ asrc, const float* __restrict__ adst,
                        const int* __restrict__ startp, const int* __restrict__ deg,
                        const int* __restrict__ col, const float* __restrict__ bias,
                        float* __restrict__ out, float* __restrict__ ostats, int n)
{
    __shared__ float stage[4][64];
    int wv = (blockIdx.x * blockDim.x + threadIdx.x) >> 6;
    int lane = threadIdx.x & 63;
    int w = threadIdx.x >> 6;
    const int g = lane >> 4, l16 = lane & 15;
    float4 o = make_float4(0.f, 0.f, 0.f, 0.f);
    const unsigned int* hbu = reinterpret_cast<const unsigned int*>(hb);  // 32 uints/row
    if (wv < n) {
        const int s0 = startp[wv], d = deg[wv];
        const int dpad = (d + 7) & ~7;
        const float adv = adst[wv];
        f32x2 A01 = {0.f, 0.f}, A23 = {0.f, 0.f};
        float sm = 0.f;
        if (g == 0) {
            float ww = __expf(lrelu(asrc[wv] + adv));
            uint2 u = *reinterpret_cast<const uint2*>(&hbu[(size_t)wv * 32 + (l16 << 1)]);
            A01 = ww * bfpair(u.x);
            A23 = ww * bfpair(u.y);
            sm = ww;
        }
        #pragma unroll 4
        for (int t = g; t < dpad; t += 4) {
            int s = col[s0 + t];
            float ww = __expf(lrelu(asrc[s] + adv));
            uint2 u = *reinterpret_cast<const uint2*>(&hbu[(size_t)s * 32 + (l16 << 1)]);
            sm += ww;
            A01 += ww * bfpair(u.x);
            A23 += ww * bfpair(u.y);
        }
        #pragma unroll
        for (int off = 16; off <= 32; off <<= 1) {
            A01.x += __shfl_xor(A01.x, off); A01.y += __shfl_xor(A01.y, off);
            A23.x += __shfl_xor(A23.x, off); A23.y += __shfl_xor(A23.y, off);
            sm += __shfl_xor(sm, off);
        }
        if (g == 0) {
            float rv = 1.f / (sm + 1e-16f);
            float4 bv = *reinterpret_cast<const float4*>(&bias[l16 << 2]);
            o.x = A01.x * rv + bv.x; o.y = A01.y * rv + bv.y;
            o.z = A23.x * rv + bv.z; o.w = A23.y * rv + bv.w;
            *reinterpret_cast<float4*>(&out[(size_t)wv * 64 + (l16 << 2)]) = o;
        }
    }
    if (g == 0)
        *reinterpret_cast<float4*>(&stage[w][l16 << 2]) = o;
    __syncthreads();
    int tid = threadIdx.x;
    if (tid < 64) {
        float s = 0.f, s2 = 0.f;
        #pragma unroll
        for (int k = 0; k < 4; k++) {
            float v = stage[k][tid];
            s += v; s2 += v * v;
        }
        float* dst = ostats + (blockIdx.x & (NCOPY - 1)) * 128;
        atomicAdd(&dst[tid], s);
        atomicAdd(&dst[64 + tid], s2);
    }
}

// ---------------- final head: relu(bn(h)) @ lw2 + lb2 ----------------
__global__ void k_head(const float* __restrict__ h, const float* __restrict__ bnst,
                       float invN,
                       const float* __restrict__ lw2, const float* __restrict__ lb2,
                       float* __restrict__ out, int n)
{
    __shared__ float muH[64], rsH[64];
    int tid = threadIdx.x;
    if (tid < 64) {
        float s = 0.f, s2 = 0.f;
        #pragma unroll
        for (int c = 0; c < NCOPY; c++) {
            s  += bnst[c * 128 + tid];
            s2 += bnst[c * 128 + 64 + tid];
        }
        float m = s * invN;
        float var = s2 * invN - m * m;
        muH[tid] = m;
        rsH[tid] = rsqrtf(var + EPS_BN);
    }
    __syncthreads();
    int wv = (blockIdx.x * blockDim.x + threadIdx.x) >> 6;
    int lane = threadIdx.x & 63;
    if (wv >= n) return;
    float v = fmaxf((h[(size_t)wv * 64 + lane] - muH[lane]) * rsH[lane], 0.f);
    float c0 = v * lw2[lane * 2 + 0];
    float c1 = v * lw2[lane * 2 + 1];
    #pragma unroll
    for (int off = 32; off; off >>= 1) {
        c0 += __shfl_xor(c0, off);
        c1 += __shfl_xor(c1, off);
    }
    if (lane == 0) {
        out[wv * 2 + 0] = c0 + lb2[0];
        out[wv * 2 + 1] = c1 + lb2[1];
    }
}

extern "C" void kernel_launch(void* const* d_in, const int* in_sizes, int n_in,
                              void* d_out, int out_size, void* d_ws, size_t ws_size,
                              hipStream_t stream)
{
    const float* x   = (const float*)d_in[0];
    const int*   ei  = (const int*)d_in[1];
    const float* W0  = (const float*)d_in[2];
    const float* as0 = (const float*)d_in[3];
    const float* ad0 = (const float*)d_in[4];
    const float* b0  = (const float*)d_in[5];
    const float* W1  = (const float*)d_in[6];
    const float* as1 = (const float*)d_in[7];
    const float* ad1 = (const float*)d_in[8];
    const float* b1  = (const float*)d_in[9];
    const float* W2  = (const float*)d_in[10];
    const float* as2 = (const float*)d_in[11];
    const float* ad2 = (const float*)d_in[12];
    const float* b2  = (const float*)d_in[13];
    const float* lw1 = (const float*)d_in[14];
    const float* lb1 = (const float*)d_in[15];
    const float* lw2 = (const float*)d_in[16];
    const float* lb2 = (const float*)d_in[17];
    float* out = (float*)d_out;

    const int n = in_sizes[0] / F_IN;   // 50000
    const int e = in_sizes[1] / 2;      // 800000
    const int nbin = (n + 255) >> 8;    // 196

    char* ws = (char*)d_ws;
    size_t off = 0;
    auto alloc = [&](size_t bytes) -> void* {
        void* p = ws + off;
        off += (bytes + 255) & ~(size_t)255;
        return p;
    };
    unsigned short* aggx = (unsigned short*)alloc((size_t)n * 512 * 2);     // 51.2 MB
    unsigned short* Hb   = aggx;                                            // layers 1/2 gather buf
    unsigned int*   SE   = (unsigned int*)aggx;                             // sorted edges (dead before aggx4)
    unsigned short* out0b = (unsigned short*)alloc((size_t)n * 256 * 2);    // 25.6 MB
    int* H  = (int*)out0b;                                                  // hist (dead before gemm_bd)
    int* Hc = (int*)(out0b + 512 * 1024);                                   // scan
    float* B64 = (float*)alloc((size_t)n * 64 * 4);                         // 12.8 MB
    unsigned short* xb = (unsigned short*)alloc((size_t)(n + 1) * 128 * 2); // 12.8 MB (+dummy row)
    float* g3 = (float*)xb;
    float* a_src = (float*)alloc(((size_t)n * 4 + 8) * 4);
    float* a_dst = (float*)alloc((size_t)n * 4 * 4);
    unsigned short* Wt0 = (unsigned short*)alloc(256 * 128 * 2);
    unsigned short* Wt1 = (unsigned short*)alloc(64 * 256 * 2);
    unsigned short* Wt2 = (unsigned short*)alloc(64 * 64 * 2);
    unsigned short* Wtm = (unsigned short*)alloc(64 * 64 * 2);
    float* vsd  = (float*)alloc(1024 * 4);
    int* col    = (int*)alloc(((size_t)e + 8 * (size_t)n) * 4);             // padded CSR
    int* startp = (int*)alloc((size_t)n * 4);
    int* deg    = (int*)alloc((size_t)n * 4);
    int* bintot = (int*)alloc(512 * 4);
    int* SEbase = (int*)alloc(512 * 4);
    int* binpad = (int*)alloc(512 * 4);
    int* binbase = (int*)alloc(512 * 4);
    char* zbase = ws + off;
    float* st0 = (float*)alloc(NCOPY * 512 * 4);
    float* st1 = (float*)alloc(NCOPY * 128 * 4);
    float* st2 = (float*)alloc(NCOPY * 128 * 4);
    float* st3 = (float*)alloc(NCOPY * 128 * 4);
    size_t zsize = (size_t)((ws + off) - zbase);

    const float invN = 1.f / (float)n;

    hipMemsetAsync(zbase, 0, zsize, stream);

    const int tpb = 256;
    k_wprep_all<<<229, tpb, 0, stream>>>(W0, W1, W2, lw1, as0, ad0, Wt0, Wt1, Wt2, Wtm,
                                         vsd, a_src, n);

    const int wgrid = (n + 3) / 4;   // 12500 blocks (>= NBLK)
    // fused hist + layer-0 prep
    k_front<<<wgrid, tpb, 0, stream>>>(ei, e, nbin, H, x, vsd, xb, a_src, a_dst, n);

    // ---- rest of CSR build (counting sort; no device atomics; parallel scans) ----
    k_scanbins<<<(nbin * 64 + tpb - 1) / tpb, tpb, 0, stream>>>(H, Hc, bintot, nbin);
    k_scanbase<<<1, tpb, 0, stream>>>(bintot, SEbase, nbin);
    k_scatter<<<NBLK, tpb, 0, stream>>>(ei, e, Hc, SEbase, SE, nbin);
    k_degb<<<nbin, tpb, 0, stream>>>(SE, SEbase, deg, binpad, n);
    k_binscan<<<1, tpb, 0, stream>>>(binpad, binbase, nbin);
    k_fillb<<<nbin, tpb, 0, stream>>>(SE, SEbase, binbase, deg, col, startp, n);

    const int rowTiles = (n + 63) / 64;

    // Layer 0: x-aggregate (8-edge, packed fp32) -> block-diagonal GEMM
    k_aggx4<<<wgrid, 256, 0, stream>>>(xb, a_src, a_dst, startp, deg, col, aggx, n);
    k_gemm_bd<<<dim3(rowTiles, 4), 256, 0, stream>>>(aggx, Wt0, b0, out0b, st0, n);

    // Layer 1: GAT 256 -> 64 (bf16 A, BN fused from st0); Hb aliases aggx (dead)
    k_gemm<true, true, true><<<dim3(rowTiles, 1), 256, 0, stream>>>(
        nullptr, out0b, Wt1, nullptr, st0, invN, as1, ad1, a_src, a_dst, 1,
        nullptr, Hb, nullptr, n, 256, 64);
    k_agg1f<<<wgrid, 256, 0, stream>>>(Hb, a_src, a_dst, startp, deg, col, b1, B64, st1, n);

    // Layer 2: GAT 64 -> 64 (fp32 A from B64)
    k_gemm<true, true, false><<<dim3(rowTiles, 1), 256, 0, stream>>>(
        B64, nullptr, Wt2, nullptr, st1, invN, as2, ad2, a_src, a_dst, 1,
        nullptr, Hb, nullptr, n, 64, 64);
    k_agg1f<<<wgrid, 256, 0, stream>>>(Hb, a_src, a_dst, startp, deg, col, b2, B64, st2, n);

    // MLP: relu(bn(out2)) @ lw1 + lb1 -> g3 (aliases xb, dead); stats st3
    k_gemm<true, false, false><<<dim3(rowTiles, 1), 256, 0, stream>>>(
        B64, nullptr, Wtm, lb1, st2, invN, nullptr, nullptr, nullptr, nullptr, 1,
        g3, nullptr, st3, n, 64, 64);

    // head: relu(bn(g3)) @ lw2 + lb2
    k_head<<<wgrid, 256, 0, stream>>>(g3, st3, invN, lw2, lb2, out, n);
}